// Round 6
// baseline (1163.521 us; speedup 1.0000x reference)
//
#include <hip/hip_runtime.h>
#include <math.h>

// Problem constants
#define BB 16
#define TT 4096
#define DD 512
#define LOUT 512

typedef __attribute__((ext_vector_type(8))) _Float16 half8;
typedef __attribute__((ext_vector_type(4))) float floatx4;

// ---------------------------------------------------------------------------
// Workspace layout (bytes), total ~138.02 MB:
//   A_hi : _Float16, 16 batches x 4098 rows x 512  @ 0
//          (row b*4098+0 and b*4098+4097 are zero guard rows; data row t at
//           b*4098+1+t  -> conv halo t=-1/4096 reads guards, no branches)
//   A_lo : same shape                              @ 67141632
//   B_hi : _Float16[3*512*512] [tap][c][i]         @ 134283264
//   B_lo : same                                    @ 135856128
//   a_pre: float[65536]                            @ 137428992
//   w_main: float[65536]                           @ 137691136
//   fire_pos: int[16*1024]                         @ 137953280
//   Fcount: int[16]                                @ 138018816
// ---------------------------------------------------------------------------
#define A_HI_OFF   0
#define A_LO_OFF   67141632
#define B_HI_OFF   134283264
#define B_LO_OFF   135856128
#define APRE_OFF   137428992
#define WMAIN_OFF  137691136
#define FPOS_OFF   137953280
#define FCNT_OFF   138018816

__global__ void zero_ws(float* __restrict__ a_pre,
                        _Float16* __restrict__ A_hi,
                        _Float16* __restrict__ A_lo) {
    int idx = blockIdx.x * 256 + threadIdx.x;
    if (idx < 65536) a_pre[idx] = 0.f;
    if (idx < 16384) {                       // zero the 2x16 guard rows
        int b = idx >> 10;
        int j = idx & 1023;
        size_t row = (size_t)b * 4098 + ((j < 512) ? 0 : 4097);
        int e = j & 511;
        A_hi[row * 512 + e] = (_Float16)0.f;
        A_lo[row * 512 + e] = (_Float16)0.f;
    }
}

// hidden fp32 -> f16 hi + lo, written into the guard-padded layout
__global__ void split_hidden(const float* __restrict__ hidden,
                             _Float16* __restrict__ A_hi,
                             _Float16* __restrict__ A_lo) {
    size_t e = ((size_t)blockIdx.x * 256 + threadIdx.x) * 8;   // 33.55M elems
    const float4* src = (const float4*)(hidden + e);
    float4 v0 = src[0], v1 = src[1];
    float x[8] = {v0.x, v0.y, v0.z, v0.w, v1.x, v1.y, v1.z, v1.w};
    _Float16 hi[8], lo[8];
    #pragma unroll
    for (int j = 0; j < 8; j++) {
        hi[j] = (_Float16)x[j];
        lo[j] = (_Float16)(x[j] - (float)hi[j]);
    }
    int b = (int)(e >> 21);                 // 4096*512 = 2^21
    int rem = (int)(e & 2097151);
    int t = rem >> 9;
    int d = rem & 511;
    size_t dst = (((size_t)b * 4098 + 1 + t) << 9) + d;
    *(half8*)(A_hi + dst) = *(half8*)hi;
    *(half8*)(A_lo + dst) = *(half8*)lo;
}

// conv_w[c][i][tap] fp32 -> B_hi/B_lo [tap][c][i] f16 (B^T: rows=c, cols=i)
__global__ void repack_wsplit(const float* __restrict__ conv_w,
                              _Float16* __restrict__ B_hi,
                              _Float16* __restrict__ B_lo) {
    int idx = blockIdx.x * 256 + threadIdx.x;    // over 786432
    if (idx < 786432) {
        int tap = idx / 262144;
        int rem = idx - tap * 262144;
        int c = rem >> 9;
        int i = rem & 511;
        float v = conv_w[(c * 512 + i) * 3 + tap];
        _Float16 h = (_Float16)v;
        B_hi[idx] = h;
        B_lo[idx] = (_Float16)(v - (float)h);
    }
}

// Split-f16 MFMA conv-GEMM, fragment-direct global loads (no LDS, no barriers).
// C = Ahi*Bhi + Ahi*Blo + Alo*Bhi, fp32 accumulate. Block 128x128, 4 waves,
// wave tile 64x64 = 4x4 frags of 16x16x32. Per (kc,tap): 16 dwordx4 frag
// loads straight to VGPRs + 48 MFMAs; compiler pipelines via vmcnt.
__launch_bounds__(256, 2)
__global__ void mfma_gemm(const _Float16* __restrict__ A_hi,
                          const _Float16* __restrict__ A_lo,
                          const _Float16* __restrict__ B_hi,
                          const _Float16* __restrict__ B_lo,
                          const float* __restrict__ conv_b,
                          const float* __restrict__ out_w,
                          float* __restrict__ a_pre) {
    const int tid  = threadIdx.x;
    const int w    = tid >> 6;
    const int lane = tid & 63;
    const int wm   = w >> 1;
    const int wn   = w & 1;
    const int l15  = lane & 15;
    const int lq   = lane >> 4;

    // XCD swizzle: 4 nt-blocks of one mt land on the same XCD (bx % 8)
    const int bx = blockIdx.x;              // 0..2047
    const int x  = bx & 7;
    const int g  = bx >> 3;                 // 0..255
    const int nt = g & 3;
    const int mt = 64 * x + (g >> 2);       // 0..511
    const int b  = mt >> 5;
    const int t0 = (mt & 31) << 7;
    const int c0 = nt << 7;

    // fragment byte offsets (A_lo shares aoff; B_lo shares boff)
    int aoff[3][4], boff[3][4];
    #pragma unroll
    for (int tap = 0; tap < 3; tap++) {
        #pragma unroll
        for (int mi = 0; mi < 4; mi++) {
            int row = b * 4098 + 1 + t0 + 64 * wm + 16 * mi + l15 + tap - 1;
            aoff[tap][mi] = row * 1024 + lq * 16;
        }
        #pragma unroll
        for (int ni = 0; ni < 4; ni++) {
            int crow = tap * 512 + c0 + 64 * wn + 16 * ni + l15;
            boff[tap][ni] = crow * 1024 + lq * 16;
        }
    }

    floatx4 acc[4][4];
    #pragma unroll
    for (int mi = 0; mi < 4; mi++)
        #pragma unroll
        for (int ni = 0; ni < 4; ni++)
            acc[mi][ni] = (floatx4)(0.f);

    float u_n[4], cb_n[4];
    #pragma unroll
    for (int ni = 0; ni < 4; ni++) {
        int n = c0 + 64 * wn + 16 * ni + l15;
        u_n[ni]  = out_w[n];
        cb_n[ni] = conv_b[n];
    }

    const char* Ahc = (const char*)A_hi;
    const char* Alc = (const char*)A_lo;
    const char* Bhc = (const char*)B_hi;
    const char* Blc = (const char*)B_lo;

    for (int kc = 0; kc < 16; kc++) {
        const int koff = kc * 64;
        #pragma unroll
        for (int tap = 0; tap < 3; tap++) {
            half8 ah[4], al[4], bh[4], bl[4];
            #pragma unroll
            for (int mi = 0; mi < 4; mi++) {
                ah[mi] = *(const half8*)(Ahc + aoff[tap][mi] + koff);
                al[mi] = *(const half8*)(Alc + aoff[tap][mi] + koff);
            }
            #pragma unroll
            for (int ni = 0; ni < 4; ni++) {
                bh[ni] = *(const half8*)(Bhc + boff[tap][ni] + koff);
                bl[ni] = *(const half8*)(Blc + boff[tap][ni] + koff);
            }
            #pragma unroll
            for (int mi = 0; mi < 4; mi++)
                #pragma unroll
                for (int ni = 0; ni < 4; ni++) {
                    acc[mi][ni] = __builtin_amdgcn_mfma_f32_16x16x32_f16(
                        ah[mi], bh[ni], acc[mi][ni], 0, 0, 0);
                    acc[mi][ni] = __builtin_amdgcn_mfma_f32_16x16x32_f16(
                        ah[mi], bl[ni], acc[mi][ni], 0, 0, 0);
                    acc[mi][ni] = __builtin_amdgcn_mfma_f32_16x16x32_f16(
                        al[mi], bh[ni], acc[mi][ni], 0, 0, 0);
                }
        }
    }

    // epilogue: relu(acc + cb) dot u over n; reduce across the 16 col-lanes
    float s[4][4];
    #pragma unroll
    for (int mi = 0; mi < 4; mi++)
        #pragma unroll
        for (int rg = 0; rg < 4; rg++) {
            float t = 0.f;
            #pragma unroll
            for (int ni = 0; ni < 4; ni++) {
                float y = acc[mi][ni][rg] + cb_n[ni];
                y = y > 0.f ? y : 0.f;
                t = fmaf(y, u_n[ni], t);
            }
            s[mi][rg] = t;
        }
    #pragma unroll
    for (int mi = 0; mi < 4; mi++)
        #pragma unroll
        for (int rg = 0; rg < 4; rg++) {
            #pragma unroll
            for (int off = 1; off < 16; off <<= 1)
                s[mi][rg] += __shfl_xor(s[mi][rg], off);
        }
    if (l15 == 0) {
        #pragma unroll
        for (int mi = 0; mi < 4; mi++)
            #pragma unroll
            for (int rg = 0; rg < 4; rg++) {
                int m = 64 * wm + 16 * mi + 4 * lq + rg;
                atomicAdd(&a_pre[b * TT + t0 + m], s[mi][rg]);
            }
    }
}

// Per-batch: sigmoid -> token_num -> rescale -> sequential CIF scan (pipelined).
__global__ void cif_scan(const float* __restrict__ a_pre,
                         const float* __restrict__ mask,
                         const float* __restrict__ tll,
                         const float* __restrict__ out_bias,
                         float* __restrict__ out_tn,
                         float* __restrict__ out_alphas,
                         float* __restrict__ out_peak,
                         float* __restrict__ w_main,
                         int* __restrict__ fire_pos,
                         int* __restrict__ Fcount) {
    __shared__ float alpha_s[TT];
    __shared__ float wm_s[TT];
    __shared__ float fires_s[TT];
    __shared__ int   fp_s[1024];
    __shared__ double red[256];
    __shared__ float ratio_s;
    __shared__ int   F_sh;

    const int b = blockIdx.x;
    const int tid = threadIdx.x;
    const float ob = out_bias[0];

    double lsum = 0.0;
    for (int t = tid; t < TT; t += 256) {
        float a = a_pre[b * TT + t] + ob;
        float e = expf(-fabsf(a));
        float sg = (a >= 0.f) ? (1.f / (1.f + e)) : (e / (1.f + e));
        float af = sg;
        af = af > 0.f ? af : 0.f;
        af = af * mask[b * TT + t];
        alpha_s[t] = af;
        lsum += (double)af;
    }
    red[tid] = lsum;
    __syncthreads();
    for (int off = 128; off > 0; off >>= 1) {
        if (tid < off) red[tid] += red[tid + off];
        __syncthreads();
    }
    if (tid == 0) {
        float tn = (float)red[0];
        out_tn[b] = tn;
        ratio_s = tll[b] / tn;
    }
    __syncthreads();
    const float ratio = ratio_s;
    for (int t = tid; t < TT; t += 256) {
        float a = alpha_s[t] * ratio;
        alpha_s[t] = a;
        out_alphas[b * TT + t] = a;
    }
    __syncthreads();

    if (tid == 0) {
        float I = 0.f;
        int F = 0;
        float4 n0 = *(const float4*)&alpha_s[0];
        float4 n1 = *(const float4*)&alpha_s[4];
        for (int t8 = 0; t8 < TT; t8 += 8) {
            float av[8];
            *(float4*)&av[0] = n0;
            *(float4*)&av[4] = n1;
            if (t8 + 8 < TT) {
                n0 = *(const float4*)&alpha_s[t8 + 8];
                n1 = *(const float4*)&alpha_s[t8 + 12];
            }
            #pragma unroll
            for (int j = 0; j < 8; j++) {
                float a = av[j];
                float In = I + a;
                fires_s[t8 + j] = In;
                bool fire = (In >= 1.0f);
                wm_s[t8 + j] = fire ? (1.0f - I) : a;
                int Fc = (F < 1023) ? F : 1023;
                fp_s[Fc] = t8 + j;
                F += fire ? 1 : 0;
                I = fire ? (In - 1.0f) : In;
            }
        }
        F_sh = (F > 1024) ? 1024 : F;
        Fcount[b] = F_sh;
    }
    __syncthreads();
    const int F = F_sh;
    for (int t = tid; t < TT; t += 256) {
        out_peak[b * TT + t] = fires_s[t];
        w_main[b * TT + t]   = wm_s[t];
    }
    for (int s = tid; s < F; s += 256)
        fire_pos[b * 1024 + s] = fp_s[s];
}

// acoustic_embeds[b,s,:] = spill(prev fire) + sum over contiguous t-segment.
__global__ void cif_scatter(const float* __restrict__ hidden,
                            const float* __restrict__ alphas,
                            const float* __restrict__ w_main,
                            const int* __restrict__ fire_pos,
                            const int* __restrict__ Fcount,
                            float* __restrict__ out_emb) {
    const int s = blockIdx.x;
    const int b = blockIdx.y;
    const int tid = threadIdx.x;   // 0..127 -> d = 4*tid
    const int F = Fcount[b];

    float4 acc = make_float4(0.f, 0.f, 0.f, 0.f);
    if (s < F) {
        const int t_hi = fire_pos[b * 1024 + s];
        const int t_lo = (s > 0) ? fire_pos[b * 1024 + s - 1] : 0;
        for (int t = t_lo; t <= t_hi; t++) {
            float w;
            if (s > 0 && t == t_lo)
                w = alphas[b * TT + t] - w_main[b * TT + t];
            else
                w = w_main[b * TT + t];
            const float4 h = *(const float4*)(hidden + ((size_t)(b * TT + t)) * DD + 4 * tid);
            acc.x = fmaf(w, h.x, acc.x);
            acc.y = fmaf(w, h.y, acc.y);
            acc.z = fmaf(w, h.z, acc.z);
            acc.w = fmaf(w, h.w, acc.w);
        }
    }
    *(float4*)(out_emb + ((size_t)(b * LOUT + s)) * DD + 4 * tid) = acc;
}

extern "C" void kernel_launch(void* const* d_in, const int* in_sizes, int n_in,
                              void* d_out, int out_size, void* d_ws, size_t ws_size,
                              hipStream_t stream) {
    const float* hidden  = (const float*)d_in[0];
    const float* mask    = (const float*)d_in[1];
    const float* tll     = (const float*)d_in[2];
    const float* conv_w  = (const float*)d_in[3];
    const float* conv_b  = (const float*)d_in[4];
    const float* out_w   = (const float*)d_in[5];
    const float* out_b   = (const float*)d_in[6];

    float* out        = (float*)d_out;
    float* out_emb    = out;
    float* out_tn     = out + 4194304;
    float* out_alphas = out + 4194320;
    float* out_peak   = out + 4259856;

    char* ws = (char*)d_ws;
    _Float16* A_hi   = (_Float16*)(ws + A_HI_OFF);
    _Float16* A_lo   = (_Float16*)(ws + A_LO_OFF);
    _Float16* B_hi   = (_Float16*)(ws + B_HI_OFF);
    _Float16* B_lo   = (_Float16*)(ws + B_LO_OFF);
    float* a_pre     = (float*)(ws + APRE_OFF);
    float* w_main    = (float*)(ws + WMAIN_OFF);
    int*   fire_pos  = (int*)(ws + FPOS_OFF);
    int*   Fcount    = (int*)(ws + FCNT_OFF);

    zero_ws<<<256, 256, 0, stream>>>(a_pre, A_hi, A_lo);
    split_hidden<<<16384, 256, 0, stream>>>(hidden, A_hi, A_lo);
    repack_wsplit<<<3072, 256, 0, stream>>>(conv_w, B_hi, B_lo);
    mfma_gemm<<<2048, 256, 0, stream>>>(A_hi, A_lo, B_hi, B_lo,
                                        conv_b, out_w, a_pre);
    cif_scan<<<16, 256, 0, stream>>>(a_pre, mask, tll, out_b,
                                     out_tn, out_alphas, out_peak,
                                     w_main, fire_pos, Fcount);
    cif_scatter<<<dim3(512, 16), 128, 0, stream>>>(hidden, out_alphas, w_main,
                                                   fire_pos, Fcount, out_emb);
}